// Round 8
// baseline (990.757 us; speedup 1.0000x reference)
//
#include <hip/hip_runtime.h>
#include <stdint.h>

#define HW 262144              // 512*512
#define NB 32                  // batch
#define TOPK 4096
#define NTOTAL (NB * HW)       // 8388608
#define GBLK 4096              // elements per block for histB/gather

// ---------------- ws layout (bytes) ----------------
// d:       uint32[NTOTAL]             @ 0          (33,554,432)
// winners: uint64[NB][8192]           @ 33554432   ( 2,097,152)
// hist16:  uint32[NB][65536]          @ 35651584   ( 8,388,608)  (reused pass A+B)
// stateA:  uint32[NB][2] (P16,rem16)  @ 44040192   (       256)
// stateB:  uint32[NB]   (T)           @ 44040448   (       128)
// cnt:     uint32[NB]                 @ 44040576   (       128)
#define OFF_WIN 33554432
#define OFF_H16 35651584
#define OFF_STA 44040192
#define OFF_STB 44040448
#define OFF_CNT 44040576

__device__ __forceinline__ uint32_t rotl32(uint32_t x, int d) {
  return (x << d) | (x >> (32 - d));
}

// JAX threefry2x32, key = (0, 42). Verified bit-exact R6. DO NOT TOUCH.
__device__ __forceinline__ void threefry2x32_k42(uint32_t x0, uint32_t x1,
                                                 uint32_t& o0, uint32_t& o1) {
  const uint32_t ks0 = 0u;
  const uint32_t ks1 = 42u;
  const uint32_t ks2 = 0x1BD11BDAu ^ 0u ^ 42u;
  x0 += ks0;
  x1 += ks1;
#define TF_ROUND(r) { x0 += x1; x1 = rotl32(x1, (r)); x1 ^= x0; }
  TF_ROUND(13) TF_ROUND(15) TF_ROUND(26) TF_ROUND(6)
  x0 += ks1; x1 += ks2 + 1u;
  TF_ROUND(17) TF_ROUND(29) TF_ROUND(16) TF_ROUND(24)
  x0 += ks2; x1 += ks0 + 2u;
  TF_ROUND(13) TF_ROUND(15) TF_ROUND(26) TF_ROUND(6)
  x0 += ks0; x1 += ks1 + 3u;
  TF_ROUND(17) TF_ROUND(29) TF_ROUND(16) TF_ROUND(24)
  x0 += ks1; x1 += ks2 + 4u;
  TF_ROUND(13) TF_ROUND(15) TF_ROUND(26) TF_ROUND(6)
  x0 += ks2; x1 += ks0 + 5u;
#undef TF_ROUND
  o0 = x0;
  o1 = x1;
}

// Bit-exact Eigen plog_float. Verified absmax=0 in R6. DO NOT TOUCH.
__device__ __forceinline__ float eigen_plogf(float xin) {
#pragma clang fp contract(off)
  uint32_t ux = __float_as_uint(xin);
  int e_int = (int)(ux >> 23) - 126;
  float x = __uint_as_float((ux & 0x007fffffu) | 0x3f000000u);
  float e = (float)e_int;
  const float SQRTHF = 0.707106781186547524f;
  bool m = (x < SQRTHF);
  float tmp = m ? x : 0.0f;
  x = x - 1.0f;
  e = e - (m ? 1.0f : 0.0f);
  x = x + tmp;
  float x2 = x * x;
  float x3 = x2 * x;
  float y  = fmaf(7.0376836292e-2f,  x, -1.1514610310e-1f);
  float y1 = fmaf(-1.2420140846e-1f, x,  1.4249322787e-1f);
  float y2 = fmaf(2.0000714765e-1f,  x, -2.4999993993e-1f);
  y  = fmaf(y,  x,  1.1676998740e-1f);
  y1 = fmaf(y1, x, -1.6668057665e-1f);
  y2 = fmaf(y2, x,  3.3333331174e-1f);
  y  = fmaf(y,  x3, y1);
  y  = fmaf(y,  x3, y2);
  y  = y * x3;
  float ey1 = e * -2.12194440e-4f;
  float t2  = x2 * 0.5f;
  y = y + ey1;
  x = x - t2;
  float ey2 = e * 0.693359375f;
  x = x + y;
  x = x + ey2;
  return x;
}

// Bit-exact numpy SIMD f32 np.log (rational). Verified R6. DO NOT TOUCH.
__device__ __forceinline__ float np_logf(float xin) {
#pragma clang fp contract(off)
  uint32_t ux = __float_as_uint(xin);
  int e2 = (int)(ux >> 23) - 127;
  float mant = __uint_as_float((ux & 0x007fffffu) | 0x3f800000u);
  if (mant >= 1.5f) { mant = mant * 0.5f; e2 += 1; }
  float e = (float)e2;
  float t = mant - 1.0f;
  float num = fmaf(2.589979117907922693523e-02f, t, 3.808837741388407920751e-01f);
  num = fmaf(num, t, 1.480000633400055983228e+00f);
  num = fmaf(num, t, 2.112677543073053063722e+00f);
  num = fmaf(num, t, 9.999999999999998702752e-01f);
  num = num * t;
  float den = fmaf(5.875095403124574342950e-03f, t, 1.546476374983906719538e-01f);
  den = fmaf(den, t, 9.864942958519418960339e-01f);
  den = fmaf(den, t, 2.453006071784736363091e+00f);
  den = fmaf(den, t, 2.612677543073109236779e+00f);
  den = fmaf(den, t, 1.0f);
  float r = num / den;
  return fmaf(e, 0.693147182464599609375f, r);
}

// score -> descending-order uint32 key. Verified R6. DO NOT TOUCH.
__device__ __forceinline__ uint32_t order_key(const float* __restrict__ flows,
                                              int p, uint32_t bits) {
#pragma clang fp contract(off)
  int b = p >> 18;
  int j = p & (HW - 1);
  const float* fb = flows + ((size_t)b << 19);
  float x = fb[j];
  float y = fb[j + HW];
  float xx = x * x;
  float yy = y * y;
  float ss = xx + yy;
  float sq = (float)sqrt((double)ss);
  float dist = (float)((double)sq / (double)0.07f);
  float logits = np_logf(dist + 1e-20f);
  float f = __uint_as_float((bits >> 9) | 0x3f800000u) - 1.0f;
  float u = fmaxf(f, 1.17549435e-38f);
  float g = -eigen_plogf(-eigen_plogf(u));
  float s = logits + g;
  uint32_t mm = __float_as_uint(s);
  mm = (mm & 0x80000000u) ? ~mm : (mm | 0x80000000u);
  return ~mm;
}

// keys + fused pass-A (top-16-bit) histogram
__global__ __launch_bounds__(256) void k_compute(const float* __restrict__ flows,
                                                 uint32_t* __restrict__ d,
                                                 uint32_t* __restrict__ hist16) {
  int p = blockIdx.x * 256 + threadIdx.x;
  uint32_t o0, o1;
  threefry2x32_k42(0u, (uint32_t)p, o0, o1);
  uint32_t dv = order_key(flows, p, o0 ^ o1);
  d[p] = dv;
  int b = p >> 18;
  atomicAdd(&hist16[((uint32_t)b << 16) + (dv >> 16)], 1u);
}

// per-batch: scan 65536 bins, find 16-bit prefix P16 + rem16; zero bins for pass B
__global__ __launch_bounds__(1024) void k_scan16(uint32_t* __restrict__ hist16,
                                                 uint32_t* __restrict__ stateA) {
  int b = blockIdx.x;
  uint32_t* h = hist16 + ((uint32_t)b << 16);
  int base = threadIdx.x * 64;
  uint32_t s = 0;
  for (int i = 0; i < 64; ++i) s += h[base + i];
  __shared__ uint32_t ls[1024];
  ls[threadIdx.x] = s;
  __syncthreads();
  for (int off = 1; off < 1024; off <<= 1) {
    uint32_t v = (threadIdx.x >= off) ? ls[threadIdx.x - off] : 0u;
    __syncthreads();
    ls[threadIdx.x] += v;
    __syncthreads();
  }
  uint32_t incl = ls[threadIdx.x];
  uint32_t excl = incl - s;
  if (excl < TOPK && TOPK <= incl) {
    uint32_t cum = excl;
    for (int i = 0; i < 64; ++i) {
      uint32_t c = h[base + i];
      if (cum + c >= TOPK) {
        stateA[2 * b] = (uint32_t)(base + i);
        stateA[2 * b + 1] = TOPK - cum;
        break;
      }
      cum += c;
    }
  }
  for (int i = 0; i < 64; ++i) h[base + i] = 0u;  // ready for pass B
}

// pass B: histogram low-16 bits of elements whose top16 == P16 (rare: ~100/batch)
__global__ __launch_bounds__(256) void k_histB(const uint32_t* __restrict__ d,
                                               const uint32_t* __restrict__ stateA,
                                               uint32_t* __restrict__ hist16) {
  int base = blockIdx.x * GBLK;
  int b = base >> 18;
  uint32_t P = stateA[2 * b];
  for (int it = 0; it < GBLK / 256; ++it) {
    int p = base + it * 256 + threadIdx.x;
    uint32_t dv = d[p];
    if ((dv >> 16) == P)
      atomicAdd(&hist16[((uint32_t)b << 16) + (dv & 0xFFFFu)], 1u);
  }
}

// per-batch: scan low-16 bins against rem16 -> exact 32-bit threshold T
__global__ __launch_bounds__(1024) void k_scanB(const uint32_t* __restrict__ hist16,
                                                const uint32_t* __restrict__ stateA,
                                                uint32_t* __restrict__ stateB) {
  int b = blockIdx.x;
  const uint32_t* h = hist16 + ((uint32_t)b << 16);
  uint32_t target = stateA[2 * b + 1];
  uint32_t P = stateA[2 * b];
  int base = threadIdx.x * 64;
  uint32_t s = 0;
  for (int i = 0; i < 64; ++i) s += h[base + i];
  __shared__ uint32_t ls[1024];
  ls[threadIdx.x] = s;
  __syncthreads();
  for (int off = 1; off < 1024; off <<= 1) {
    uint32_t v = (threadIdx.x >= off) ? ls[threadIdx.x - off] : 0u;
    __syncthreads();
    ls[threadIdx.x] += v;
    __syncthreads();
  }
  uint32_t incl = ls[threadIdx.x];
  uint32_t excl = incl - s;
  if (excl < target && target <= incl) {
    uint32_t cum = excl;
    for (int i = 0; i < 64; ++i) {
      uint32_t c = h[base + i];
      if (cum + c >= target) {
        stateB[b] = (P << 16) | (uint32_t)(base + i);
        break;
      }
      cum += c;
    }
  }
}

// LDS-staged winner gather (G12): one global atomic per block
__global__ __launch_bounds__(256) void k_gather(const uint32_t* __restrict__ d,
                                                const uint32_t* __restrict__ stateB,
                                                uint32_t* __restrict__ cnt,
                                                unsigned long long* __restrict__ winners) {
  __shared__ unsigned long long buf[GBLK];
  __shared__ uint32_t lcnt;
  __shared__ uint32_t gbase;
  int base = blockIdx.x * GBLK;
  int b = base >> 18;
  uint32_t T = stateB[b];
  if (threadIdx.x == 0) lcnt = 0u;
  __syncthreads();
  for (int it = 0; it < GBLK / 256; ++it) {
    int p = base + it * 256 + threadIdx.x;
    uint32_t dv = d[p];
    if (dv <= T) {
      uint32_t pos = atomicAdd(&lcnt, 1u);
      buf[pos] = ((unsigned long long)dv << 32) |
                 (unsigned long long)(p & (HW - 1));
    }
  }
  __syncthreads();
  uint32_t n = lcnt;
  if (threadIdx.x == 0 && n) gbase = atomicAdd(&cnt[b], n);
  __syncthreads();
  for (uint32_t i = threadIdx.x; i < n; i += 256) {
    uint32_t pos = gbase + i;
    if (pos < 8192u) winners[(size_t)b * 8192 + pos] = buf[i];
  }
}

// sort each 1024-chunk ascending (8 chunks/batch, 256 blocks -> full GPU)
__global__ __launch_bounds__(256) void k_sort1(const uint32_t* __restrict__ cnt,
                                               unsigned long long* __restrict__ winners) {
  __shared__ unsigned long long s[1024];
  int blk = blockIdx.x;
  int b = blk >> 3;
  int c = blk & 7;
  uint32_t n = cnt[b];
  if (n > 8192u) n = 8192u;
  int goff = b * 8192 + c * 1024;
  for (int l = threadIdx.x; l < 1024; l += 256)
    s[l] = ((uint32_t)(c * 1024 + l) < n) ? winners[goff + l]
                                          : 0xFFFFFFFFFFFFFFFFull;
  __syncthreads();
  for (int k = 2; k <= 1024; k <<= 1) {
    for (int j = k >> 1; j > 0; j >>= 1) {
      for (int i = threadIdx.x; i < 1024; i += 256) {
        int ixj = i ^ j;
        if (ixj > i) {
          bool up = ((i & k) == 0);
          unsigned long long a = s[i];
          unsigned long long cc = s[ixj];
          if ((a > cc) == up) { s[i] = cc; s[ixj] = a; }
        }
      }
      __syncthreads();
    }
  }
  for (int l = threadIdx.x; l < 1024; l += 256) winners[goff + l] = s[l];
}

// exact rank via 7 binary searches/winner (composite keys unique) + scatter
__global__ __launch_bounds__(1024) void k_rank(const unsigned long long* __restrict__ winners,
                                               const float* __restrict__ flows,
                                               float* __restrict__ out0,
                                               float* __restrict__ out_idx,
                                               float* __restrict__ out_masks) {
  __shared__ unsigned long long s[8192];
  int b = blockIdx.x;
  for (int i = threadIdx.x; i < 8192; i += 1024)
    s[i] = winners[(size_t)b * 8192 + i];
  __syncthreads();
  const float* fb = flows + ((size_t)b << 19);
  for (int i = threadIdx.x; i < 8192; i += 1024) {
    unsigned long long w = s[i];
    if (w == 0xFFFFFFFFFFFFFFFFull) continue;
    int rank = i & 1023;            // position within own sorted chunk
    int myc = i >> 10;
    for (int c = 0; c < 8; ++c) {
      if (c == myc) continue;
      int lo = 0, hi = 1024;
      while (lo < hi) {
        int mid = (lo + hi) >> 1;
        if (s[(c << 10) + mid] < w) lo = mid + 1; else hi = mid;
      }
      rank += lo;
    }
    if (rank < TOPK) {
      uint32_t idx = (uint32_t)(w & 0xFFFFFFFFull);
      out_idx[(size_t)b * TOPK + rank] = (float)idx;
      float x = fb[idx];
      float y = fb[idx + HW];
      size_t o = ((size_t)b * 3) * HW + idx;
      out0[o] = x;
      out0[o + HW] = y;
      out0[o + 2 * HW] = 1.0f;
      out_masks[(size_t)b * HW + idx] = 1.0f;
    }
  }
}

extern "C" void kernel_launch(void* const* d_in, const int* in_sizes, int n_in,
                              void* d_out, int out_size, void* d_ws, size_t ws_size,
                              hipStream_t stream) {
  const float* flows = (const float*)d_in[0];
  float* out = (float*)d_out;
  char* ws = (char*)d_ws;

  uint32_t* d = (uint32_t*)ws;
  unsigned long long* winners = (unsigned long long*)(ws + OFF_WIN);
  uint32_t* hist16 = (uint32_t*)(ws + OFF_H16);
  uint32_t* stateA = (uint32_t*)(ws + OFF_STA);
  uint32_t* stateB = (uint32_t*)(ws + OFF_STB);
  uint32_t* cnt = (uint32_t*)(ws + OFF_CNT);

  float* out_idx = out + (size_t)NB * 3 * HW;        // 25,165,824
  float* out_masks = out_idx + (size_t)NB * TOPK;    // 25,296,896

  // zero all outputs (sparse scatter fills winners); zero hist16+state+cnt
  hipMemsetAsync(d_out, 0, (size_t)out_size * sizeof(float), stream);
  hipMemsetAsync(ws + OFF_H16, 0, 8388608 + 512, stream);

  k_compute<<<NTOTAL / 256, 256, 0, stream>>>(flows, d, hist16);
  k_scan16<<<NB, 1024, 0, stream>>>(hist16, stateA);
  k_histB<<<NTOTAL / GBLK, 256, 0, stream>>>(d, stateA, hist16);
  k_scanB<<<NB, 1024, 0, stream>>>(hist16, stateA, stateB);
  k_gather<<<NTOTAL / GBLK, 256, 0, stream>>>(d, stateB, cnt, winners);
  k_sort1<<<NB * 8, 256, 0, stream>>>(cnt, winners);
  k_rank<<<NB, 1024, 0, stream>>>(winners, flows, out, out_idx, out_masks);
}

// Round 9
// 344.456 us; speedup vs baseline: 2.8763x; 2.8763x over previous
//
#include <hip/hip_runtime.h>
#include <stdint.h>

#define HW 262144              // 512*512
#define NB 32                  // batch
#define TOPK 4096
#define NTOTAL (NB * HW)       // 8388608
#define GBLK 4096              // elements per block for histB/gather
#define CBLK 32768             // elements per block for k_compute

// ---------------- ws layout (bytes) ----------------
// d:       uint32[NTOTAL]             @ 0          (33,554,432)
// winners: uint64[NB][8192]           @ 33554432   ( 2,097,152)
// histA:   uint32[NB][16384]          @ 35651584   ( 2,097,152)
// histB:   uint32[NB][16384]          @ 37748736   ( 2,097,152)
// stateA:  uint32[NB][2] (B, rem)     @ 39845888   (       256)
// stateT:  uint32[NB]   (T)           @ 39846144   (       128)
// flag:    uint32[NB]                 @ 39846272   (       128)
// cnt:     uint32[NB]                 @ 39846400   (       128)
#define OFF_WIN 33554432
#define OFF_HA  35651584
#define OFF_HB  37748736
#define OFF_STA 39845888
#define OFF_STT 39846144
#define OFF_FLG 39846272
#define OFF_CNT 39846400

__device__ __forceinline__ uint32_t rotl32(uint32_t x, int d) {
  return (x << d) | (x >> (32 - d));
}

// JAX threefry2x32, key = (0, 42). Verified bit-exact R6. DO NOT TOUCH.
__device__ __forceinline__ void threefry2x32_k42(uint32_t x0, uint32_t x1,
                                                 uint32_t& o0, uint32_t& o1) {
  const uint32_t ks0 = 0u;
  const uint32_t ks1 = 42u;
  const uint32_t ks2 = 0x1BD11BDAu ^ 0u ^ 42u;
  x0 += ks0;
  x1 += ks1;
#define TF_ROUND(r) { x0 += x1; x1 = rotl32(x1, (r)); x1 ^= x0; }
  TF_ROUND(13) TF_ROUND(15) TF_ROUND(26) TF_ROUND(6)
  x0 += ks1; x1 += ks2 + 1u;
  TF_ROUND(17) TF_ROUND(29) TF_ROUND(16) TF_ROUND(24)
  x0 += ks2; x1 += ks0 + 2u;
  TF_ROUND(13) TF_ROUND(15) TF_ROUND(26) TF_ROUND(6)
  x0 += ks0; x1 += ks1 + 3u;
  TF_ROUND(17) TF_ROUND(29) TF_ROUND(16) TF_ROUND(24)
  x0 += ks1; x1 += ks2 + 4u;
  TF_ROUND(13) TF_ROUND(15) TF_ROUND(26) TF_ROUND(6)
  x0 += ks2; x1 += ks0 + 5u;
#undef TF_ROUND
  o0 = x0;
  o1 = x1;
}

// Bit-exact Eigen plog_float. Verified absmax=0 in R6. DO NOT TOUCH.
__device__ __forceinline__ float eigen_plogf(float xin) {
#pragma clang fp contract(off)
  uint32_t ux = __float_as_uint(xin);
  int e_int = (int)(ux >> 23) - 126;
  float x = __uint_as_float((ux & 0x007fffffu) | 0x3f000000u);
  float e = (float)e_int;
  const float SQRTHF = 0.707106781186547524f;
  bool m = (x < SQRTHF);
  float tmp = m ? x : 0.0f;
  x = x - 1.0f;
  e = e - (m ? 1.0f : 0.0f);
  x = x + tmp;
  float x2 = x * x;
  float x3 = x2 * x;
  float y  = fmaf(7.0376836292e-2f,  x, -1.1514610310e-1f);
  float y1 = fmaf(-1.2420140846e-1f, x,  1.4249322787e-1f);
  float y2 = fmaf(2.0000714765e-1f,  x, -2.4999993993e-1f);
  y  = fmaf(y,  x,  1.1676998740e-1f);
  y1 = fmaf(y1, x, -1.6668057665e-1f);
  y2 = fmaf(y2, x,  3.3333331174e-1f);
  y  = fmaf(y,  x3, y1);
  y  = fmaf(y,  x3, y2);
  y  = y * x3;
  float ey1 = e * -2.12194440e-4f;
  float t2  = x2 * 0.5f;
  y = y + ey1;
  x = x - t2;
  float ey2 = e * 0.693359375f;
  x = x + y;
  x = x + ey2;
  return x;
}

// Bit-exact numpy SIMD f32 np.log (rational). Verified R6. DO NOT TOUCH.
__device__ __forceinline__ float np_logf(float xin) {
#pragma clang fp contract(off)
  uint32_t ux = __float_as_uint(xin);
  int e2 = (int)(ux >> 23) - 127;
  float mant = __uint_as_float((ux & 0x007fffffu) | 0x3f800000u);
  if (mant >= 1.5f) { mant = mant * 0.5f; e2 += 1; }
  float e = (float)e2;
  float t = mant - 1.0f;
  float num = fmaf(2.589979117907922693523e-02f, t, 3.808837741388407920751e-01f);
  num = fmaf(num, t, 1.480000633400055983228e+00f);
  num = fmaf(num, t, 2.112677543073053063722e+00f);
  num = fmaf(num, t, 9.999999999999998702752e-01f);
  num = num * t;
  float den = fmaf(5.875095403124574342950e-03f, t, 1.546476374983906719538e-01f);
  den = fmaf(den, t, 9.864942958519418960339e-01f);
  den = fmaf(den, t, 2.453006071784736363091e+00f);
  den = fmaf(den, t, 2.612677543073109236779e+00f);
  den = fmaf(den, t, 1.0f);
  float r = num / den;
  return fmaf(e, 0.693147182464599609375f, r);
}

// score -> descending-order uint32 key. Verified R6. DO NOT TOUCH.
__device__ __forceinline__ uint32_t order_key(const float* __restrict__ flows,
                                              int p, uint32_t bits) {
#pragma clang fp contract(off)
  int b = p >> 18;
  int j = p & (HW - 1);
  const float* fb = flows + ((size_t)b << 19);
  float x = fb[j];
  float y = fb[j + HW];
  float xx = x * x;
  float yy = y * y;
  float ss = xx + yy;
  float sq = (float)sqrt((double)ss);
  float dist = (float)((double)sq / (double)0.07f);
  float logits = np_logf(dist + 1e-20f);
  float f = __uint_as_float((bits >> 9) | 0x3f800000u) - 1.0f;
  float u = fmaxf(f, 1.17549435e-38f);
  float g = -eigen_plogf(-eigen_plogf(u));
  float s = logits + g;
  uint32_t mm = __float_as_uint(s);
  mm = (mm & 0x80000000u) ? ~mm : (mm | 0x80000000u);
  return ~mm;
}

// keys + fused top-14-bit histogram in LDS (G12: aggregate before atomic)
__global__ __launch_bounds__(1024) void k_compute(const float* __restrict__ flows,
                                                  uint32_t* __restrict__ d,
                                                  uint32_t* __restrict__ histA) {
  __shared__ uint32_t lh[16384];   // 64 KB
  for (int i = threadIdx.x; i < 16384; i += 1024) lh[i] = 0u;
  __syncthreads();
  int base = blockIdx.x * CBLK;
  int b = base >> 18;
  for (int it = 0; it < CBLK / 1024; ++it) {
    int p = base + it * 1024 + threadIdx.x;
    uint32_t o0, o1;
    threefry2x32_k42(0u, (uint32_t)p, o0, o1);
    uint32_t dv = order_key(flows, p, o0 ^ o1);
    d[p] = dv;
    atomicAdd(&lh[dv >> 18], 1u);
  }
  __syncthreads();
  uint32_t* hb = histA + ((uint32_t)b << 14);
  for (int i = threadIdx.x; i < 16384; i += 1024) {
    uint32_t c = lh[i];
    if (c) atomicAdd(&hb[i], c);   // coalesced, 8 blocks/batch contending
  }
}

// per-batch: scan 16384 top-14 bins -> bin B, rem, provisional T, overflow flag
__global__ __launch_bounds__(1024) void k_scanA(const uint32_t* __restrict__ histA,
                                                uint32_t* __restrict__ stateA,
                                                uint32_t* __restrict__ stateT,
                                                uint32_t* __restrict__ flag) {
  int b = blockIdx.x;
  const uint32_t* h = histA + ((uint32_t)b << 14);
  int base = threadIdx.x * 16;
  uint32_t s = 0;
  for (int i = 0; i < 16; ++i) s += h[base + i];
  __shared__ uint32_t ls[1024];
  ls[threadIdx.x] = s;
  __syncthreads();
  for (int off = 1; off < 1024; off <<= 1) {
    uint32_t v = (threadIdx.x >= off) ? ls[threadIdx.x - off] : 0u;
    __syncthreads();
    ls[threadIdx.x] += v;
    __syncthreads();
  }
  uint32_t incl = ls[threadIdx.x];
  uint32_t excl = incl - s;
  if (excl < TOPK && TOPK <= incl) {
    uint32_t cum = excl;
    for (int i = 0; i < 16; ++i) {
      uint32_t c = h[base + i];
      if (cum + c >= TOPK) {
        uint32_t B = (uint32_t)(base + i);
        stateA[2 * b] = B;
        stateA[2 * b + 1] = TOPK - cum;          // rank remaining inside bin B
        stateT[b] = (B << 18) | 0x3FFFFu;        // end-of-bin threshold
        flag[b] = (cum + c > 8192u) ? 1u : 0u;   // winners cap check
        break;
      }
      cum += c;
    }
  }
}

// fallback pass B (rare): conditioned histogram of bits [4:17]
__global__ __launch_bounds__(256) void k_histB(const uint32_t* __restrict__ d,
                                               const uint32_t* __restrict__ stateA,
                                               const uint32_t* __restrict__ flag,
                                               uint32_t* __restrict__ histB) {
  int base = blockIdx.x * GBLK;
  int b = base >> 18;
  if (flag[b] == 0u) return;                     // early-out (normal case)
  uint32_t B = stateA[2 * b];
  for (int it = 0; it < GBLK / 256; ++it) {
    int p = base + it * 256 + threadIdx.x;
    uint32_t dv = d[p];
    if ((dv >> 18) == B)
      atomicAdd(&histB[((uint32_t)b << 14) + ((dv >> 4) & 0x3FFFu)], 1u);
  }
}

__global__ __launch_bounds__(1024) void k_scanB(const uint32_t* __restrict__ histB,
                                                const uint32_t* __restrict__ stateA,
                                                const uint32_t* __restrict__ flag,
                                                uint32_t* __restrict__ stateT) {
  int b = blockIdx.x;
  if (flag[b] == 0u) return;
  const uint32_t* h = histB + ((uint32_t)b << 14);
  uint32_t target = stateA[2 * b + 1];
  uint32_t B = stateA[2 * b];
  int base = threadIdx.x * 16;
  uint32_t s = 0;
  for (int i = 0; i < 16; ++i) s += h[base + i];
  __shared__ uint32_t ls[1024];
  ls[threadIdx.x] = s;
  __syncthreads();
  for (int off = 1; off < 1024; off <<= 1) {
    uint32_t v = (threadIdx.x >= off) ? ls[threadIdx.x - off] : 0u;
    __syncthreads();
    ls[threadIdx.x] += v;
    __syncthreads();
  }
  uint32_t incl = ls[threadIdx.x];
  uint32_t excl = incl - s;
  if (excl < target && target <= incl) {
    uint32_t cum = excl;
    for (int i = 0; i < 16; ++i) {
      uint32_t c = h[base + i];
      if (cum + c >= target) {
        stateT[b] = (B << 18) | ((uint32_t)(base + i) << 4) | 0xFu;
        break;
      }
      cum += c;
    }
  }
}

// LDS-staged winner gather (G12): one global atomic per block
__global__ __launch_bounds__(256) void k_gather(const uint32_t* __restrict__ d,
                                                const uint32_t* __restrict__ stateT,
                                                uint32_t* __restrict__ cnt,
                                                unsigned long long* __restrict__ winners) {
  __shared__ unsigned long long buf[GBLK];
  __shared__ uint32_t lcnt;
  __shared__ uint32_t gbase;
  int base = blockIdx.x * GBLK;
  int b = base >> 18;
  uint32_t T = stateT[b];
  if (threadIdx.x == 0) lcnt = 0u;
  __syncthreads();
  for (int it = 0; it < GBLK / 256; ++it) {
    int p = base + it * 256 + threadIdx.x;
    uint32_t dv = d[p];
    if (dv <= T) {
      uint32_t pos = atomicAdd(&lcnt, 1u);
      buf[pos] = ((unsigned long long)dv << 32) |
                 (unsigned long long)(p & (HW - 1));
    }
  }
  __syncthreads();
  uint32_t n = lcnt;
  if (threadIdx.x == 0 && n) gbase = atomicAdd(&cnt[b], n);
  __syncthreads();
  for (uint32_t i = threadIdx.x; i < n; i += 256) {
    uint32_t pos = gbase + i;
    if (pos < 8192u) winners[(size_t)b * 8192 + pos] = buf[i];
  }
}

// sort each 1024-chunk ascending (8 chunks/batch, 256 blocks -> full GPU)
__global__ __launch_bounds__(256) void k_sort1(const uint32_t* __restrict__ cnt,
                                               unsigned long long* __restrict__ winners) {
  __shared__ unsigned long long s[1024];
  int blk = blockIdx.x;
  int b = blk >> 3;
  int c = blk & 7;
  uint32_t n = cnt[b];
  if (n > 8192u) n = 8192u;
  int goff = b * 8192 + c * 1024;
  for (int l = threadIdx.x; l < 1024; l += 256)
    s[l] = ((uint32_t)(c * 1024 + l) < n) ? winners[goff + l]
                                          : 0xFFFFFFFFFFFFFFFFull;
  __syncthreads();
  for (int k = 2; k <= 1024; k <<= 1) {
    for (int j = k >> 1; j > 0; j >>= 1) {
      for (int i = threadIdx.x; i < 1024; i += 256) {
        int ixj = i ^ j;
        if (ixj > i) {
          bool up = ((i & k) == 0);
          unsigned long long a = s[i];
          unsigned long long cc = s[ixj];
          if ((a > cc) == up) { s[i] = cc; s[ixj] = a; }
        }
      }
      __syncthreads();
    }
  }
  for (int l = threadIdx.x; l < 1024; l += 256) winners[goff + l] = s[l];
}

// exact rank via 7 binary searches/winner (composite keys unique) + scatter
__global__ __launch_bounds__(1024) void k_rank(const unsigned long long* __restrict__ winners,
                                               const float* __restrict__ flows,
                                               float* __restrict__ out0,
                                               float* __restrict__ out_idx,
                                               float* __restrict__ out_masks) {
  __shared__ unsigned long long s[8192];
  int b = blockIdx.x;
  for (int i = threadIdx.x; i < 8192; i += 1024)
    s[i] = winners[(size_t)b * 8192 + i];
  __syncthreads();
  const float* fb = flows + ((size_t)b << 19);
  for (int i = threadIdx.x; i < 8192; i += 1024) {
    unsigned long long w = s[i];
    if (w == 0xFFFFFFFFFFFFFFFFull) continue;
    int rank = i & 1023;
    int myc = i >> 10;
    for (int c = 0; c < 8; ++c) {
      if (c == myc) continue;
      int lo = 0, hi = 1024;
      while (lo < hi) {
        int mid = (lo + hi) >> 1;
        if (s[(c << 10) + mid] < w) lo = mid + 1; else hi = mid;
      }
      rank += lo;
    }
    if (rank < TOPK) {
      uint32_t idx = (uint32_t)(w & 0xFFFFFFFFull);
      out_idx[(size_t)b * TOPK + rank] = (float)idx;
      float x = fb[idx];
      float y = fb[idx + HW];
      size_t o = ((size_t)b * 3) * HW + idx;
      out0[o] = x;
      out0[o + HW] = y;
      out0[o + 2 * HW] = 1.0f;
      out_masks[(size_t)b * HW + idx] = 1.0f;
    }
  }
}

extern "C" void kernel_launch(void* const* d_in, const int* in_sizes, int n_in,
                              void* d_out, int out_size, void* d_ws, size_t ws_size,
                              hipStream_t stream) {
  const float* flows = (const float*)d_in[0];
  float* out = (float*)d_out;
  char* ws = (char*)d_ws;

  uint32_t* d = (uint32_t*)ws;
  unsigned long long* winners = (unsigned long long*)(ws + OFF_WIN);
  uint32_t* histA = (uint32_t*)(ws + OFF_HA);
  uint32_t* histB = (uint32_t*)(ws + OFF_HB);
  uint32_t* stateA = (uint32_t*)(ws + OFF_STA);
  uint32_t* stateT = (uint32_t*)(ws + OFF_STT);
  uint32_t* flag = (uint32_t*)(ws + OFF_FLG);
  uint32_t* cnt = (uint32_t*)(ws + OFF_CNT);

  float* out_idx = out + (size_t)NB * 3 * HW;        // 25,165,824
  float* out_masks = out_idx + (size_t)NB * TOPK;    // 25,296,896

  // zero outputs (sparse scatter fills winners); zero hists + state + cnt
  hipMemsetAsync(d_out, 0, (size_t)out_size * sizeof(float), stream);
  hipMemsetAsync(ws + OFF_HA, 0, 4194304 + 1024, stream);

  k_compute<<<NTOTAL / CBLK, 1024, 0, stream>>>(flows, d, histA);
  k_scanA<<<NB, 1024, 0, stream>>>(histA, stateA, stateT, flag);
  k_histB<<<NTOTAL / GBLK, 256, 0, stream>>>(d, stateA, flag, histB);
  k_scanB<<<NB, 1024, 0, stream>>>(histB, stateA, flag, stateT);
  k_gather<<<NTOTAL / GBLK, 256, 0, stream>>>(d, stateT, cnt, winners);
  k_sort1<<<NB * 8, 256, 0, stream>>>(cnt, winners);
  k_rank<<<NB, 1024, 0, stream>>>(winners, flows, out, out_idx, out_masks);
}